// Round 7
// baseline (381.823 us; speedup 1.0000x reference)
//
#include <hip/hip_runtime.h>
#include <hip/hip_bf16.h>

#define BN     6
#define NQ     10000
#define DIM    256
#define HEADS  8
#define HDD    32
#define HF_    32
#define WF_    88
#define HW_    (HF_*WF_)     /* 2816 */
#define MTOT   (BN*NQ)       /* 60000 */

typedef __attribute__((ext_vector_type(8))) unsigned short ushort8_t;
typedef __attribute__((ext_vector_type(8))) short bf16x8;
typedef __attribute__((ext_vector_type(4))) float f32x4;

static __device__ inline unsigned short f2bf(float x) {
    __hip_bfloat16 b = __float2bfloat16(x);
    return *(unsigned short*)&b;
}

// ---------------------------------------------------------------------------
// K_wcvt: f32 weights -> bf16 copies. Wv(65536), Wo(32768)+Wa(16384)->Woa,
// Wi(65536), Wz(65536).
// ---------------------------------------------------------------------------
__global__ __launch_bounds__(256)
void k_wcvt(const float* __restrict__ Wv, const float* __restrict__ Wo,
            const float* __restrict__ Wa, const float* __restrict__ Wi,
            const float* __restrict__ Wz,
            unsigned short* __restrict__ Wv_bf, unsigned short* __restrict__ Woa_bf,
            unsigned short* __restrict__ Wi_bf, unsigned short* __restrict__ Wz_bf)
{
    const int i4 = (blockIdx.x*256 + threadIdx.x) * 4;
    if (i4 < 65536) {
        float4 v;
        ushort4 p;
        v = *(const float4*)(Wv+i4); p.x=f2bf(v.x);p.y=f2bf(v.y);p.z=f2bf(v.z);p.w=f2bf(v.w);
        *(ushort4*)(Wv_bf+i4) = p;
        v = *(const float4*)(Wi+i4); p.x=f2bf(v.x);p.y=f2bf(v.y);p.z=f2bf(v.z);p.w=f2bf(v.w);
        *(ushort4*)(Wi_bf+i4) = p;
        v = *(const float4*)(Wz+i4); p.x=f2bf(v.x);p.y=f2bf(v.y);p.z=f2bf(v.z);p.w=f2bf(v.w);
        *(ushort4*)(Wz_bf+i4) = p;
    }
    if (i4 < 32768) {
        float4 v = *(const float4*)(Wo+i4);
        ushort4 p; p.x=f2bf(v.x);p.y=f2bf(v.y);p.z=f2bf(v.z);p.w=f2bf(v.w);
        *(ushort4*)(Woa_bf+i4) = p;
    }
    if (i4 < 16384) {
        float4 v = *(const float4*)(Wa+i4);
        ushort4 p; p.x=f2bf(v.x);p.y=f2bf(v.y);p.z=f2bf(v.z);p.w=f2bf(v.w);
        *(ushort4*)(Woa_bf+32768+i4) = p;
    }
}

// ---------------------------------------------------------------------------
// K0: ebias[n][j] = sum_d (lvl[d]+cam[n][d]) * W_value[j][d] + b_value[j]
// ---------------------------------------------------------------------------
__global__ __launch_bounds__(256)
void k_ebias(const float* __restrict__ lvl, const float* __restrict__ cam,
             const float* __restrict__ Wv, const float* __restrict__ bv,
             float* __restrict__ ebias)
{
    const int n = blockIdx.x;
    const int j = threadIdx.x;
    __shared__ float e[DIM];
    e[j] = lvl[j] + cam[n*DIM + j];
    __syncthreads();
    const float* w = Wv + (size_t)j*DIM;
    float s = bv[j];
    for (int d = 0; d < DIM; ++d) s += e[d]*w[d];
    ebias[n*DIM + j] = s;
}

// ---------------------------------------------------------------------------
// K_mask: per-q hit flags, count scale, bias gate.
// ---------------------------------------------------------------------------
__global__ __launch_bounds__(256)
void k_mask(const int* __restrict__ bev, float* __restrict__ hitf,
            float* __restrict__ scale, float* __restrict__ biasf)
{
    const int q = blockIdx.x*256 + threadIdx.x;
    if (q >= NQ) return;
    float cnt = 0.f;
    #pragma unroll
    for (int n = 0; n < BN; ++n) {
        int hit = 0;
        #pragma unroll
        for (int z = 0; z < 4; ++z)
            hit |= (bev[(((size_t)n*NQ + q)*4 + z)*2] != 0);
        hitf[(size_t)n*NQ + q] = (float)hit;
        cnt += (float)hit;
    }
    biasf[q] = (cnt > 0.f) ? 1.f : 0.f;
    scale[q] = 1.f / fmaxf(cnt, 1.f);
}

// ---------------------------------------------------------------------------
// K_feat: transpose feat[cam][256 d][2816 p] f32 -> featT[cam][p][d] bf16.
// 64x64 tiles through LDS.
// ---------------------------------------------------------------------------
__global__ __launch_bounds__(256)
void k_feat(const float* __restrict__ feat, unsigned short* __restrict__ featT)
{
    __shared__ float Tf[64][68];
    const int cam = blockIdx.z;
    const int d0 = blockIdx.y * 64;
    const int p0 = blockIdx.x * 64;
    const int tid = threadIdx.x;
    #pragma unroll
    for (int i = 0; i < 4; ++i) {
        const int d = (tid>>4) + i*16;
        const int p4 = (tid&15)*4;
        *(float4*)&Tf[d][p4] = *(const float4*)(feat + ((size_t)cam*DIM + d0 + d)*HW_ + p0 + p4);
    }
    __syncthreads();
    const int p = tid>>2, dq = tid&3;
    unsigned short* ob = featT + ((size_t)cam*HW_ + p0 + p)*DIM + d0;
    #pragma unroll
    for (int i = 0; i < 4; ++i) {
        const int d4 = dq*4 + i*16;
        ushort4 pk;
        pk.x = f2bf(Tf[d4+0][p]); pk.y = f2bf(Tf[d4+1][p]);
        pk.z = f2bf(Tf[d4+2][p]); pk.w = f2bf(Tf[d4+3][p]);
        *(ushort4*)(ob + d4) = pk;
    }
}

// ---------------------------------------------------------------------------
// K1: value GEMM via MFMA.  D[p][c] = featT[p][k] · Wv_bf[c][k] + ebias[c].
// Block tile 128p x 64c, K-chunks of 64.  value_bf[(cam*8+h)*HW+p][c&31].
// ---------------------------------------------------------------------------
__global__ __launch_bounds__(256)
void k_value_mfma(const unsigned short* __restrict__ featT,
                  const unsigned short* __restrict__ Wv_bf,
                  const float* __restrict__ ebias,
                  unsigned short* __restrict__ value_bf)
{
    __shared__ unsigned short Ap[128][72];
    __shared__ unsigned short Bc[64][72];
    const int cam = blockIdx.z;
    const int p0 = blockIdx.x * 128;
    const int c0 = blockIdx.y * 64;
    const int tid = threadIdx.x;
    const int lane = tid & 63, wave = tid >> 6;
    const int quad = lane >> 4, l15 = lane & 15;
    f32x4 acc[2][4] = {};
    const unsigned short* fbase = featT + ((size_t)cam*HW_ + p0)*DIM;

    for (int k0 = 0; k0 < DIM; k0 += 64) {
        #pragma unroll
        for (int i = 0; i < 4; ++i) {
            const int row = (tid>>3) + i*32;
            const int k8 = (tid&7)*8;
            *(ushort8_t*)&Ap[row][k8] = *(const ushort8_t*)(fbase + (size_t)row*DIM + k0 + k8);
        }
        #pragma unroll
        for (int i = 0; i < 2; ++i) {
            const int row = (tid>>3) + i*32;
            const int k8 = (tid&7)*8;
            *(ushort8_t*)&Bc[row][k8] = *(const ushort8_t*)(Wv_bf + (size_t)(c0+row)*DIM + k0 + k8);
        }
        __syncthreads();
        #pragma unroll
        for (int s = 0; s < 2; ++s) {
            const int kf = s*32 + quad*8;
            bf16x8 a[2], b[4];
            #pragma unroll
            for (int mt = 0; mt < 2; ++mt)
                a[mt] = *(const bf16x8*)&Ap[(wave*2+mt)*16 + l15][kf];
            #pragma unroll
            for (int nt = 0; nt < 4; ++nt)
                b[nt] = *(const bf16x8*)&Bc[nt*16 + l15][kf];
            #pragma unroll
            for (int mt = 0; mt < 2; ++mt)
                #pragma unroll
                for (int nt = 0; nt < 4; ++nt)
                    acc[mt][nt] = __builtin_amdgcn_mfma_f32_16x16x32_bf16(a[mt], b[nt], acc[mt][nt], 0,0,0);
        }
        __syncthreads();
    }
    #pragma unroll
    for (int nt = 0; nt < 4; ++nt) {
        const int c = c0 + nt*16 + l15;
        const float eb = ebias[cam*DIM + c];
        const int h = c >> 5, cc = c & 31;
        unsigned short* vb = value_bf + (size_t)(cam*HEADS + h)*HW_*HDD + cc;
        #pragma unroll
        for (int mt = 0; mt < 2; ++mt)
            #pragma unroll
            for (int r = 0; r < 4; ++r) {
                const int p = p0 + (wave*2+mt)*16 + quad*4 + r;
                vb[(size_t)p*HDD] = f2bf(acc[mt][nt][r] + eb);
            }
    }
}

// ---------------------------------------------------------------------------
// K2a: off/attn GEMM with fused Qr+Pe add/convert, B reg-prefetch, LDS
// epilogue with contiguous stores.  NEW vs r6: softmax over the 8 attn
// logits per (row,h) is applied IN the epilogue (VALU here is 96% idle),
// so attw_ws now stores PROBABILITIES and k_sample skips softmax entirely.
// ---------------------------------------------------------------------------
__global__ __launch_bounds__(256, 3)
void k_offattn(const float* __restrict__ Qr, const float* __restrict__ Pe,
               const unsigned short* __restrict__ Woa_bf,
               const float* __restrict__ boff, const float* __restrict__ battn,
               float* __restrict__ off_ws, float* __restrict__ attw_ws)
{
    __shared__ char smraw[32*204*4];
    unsigned short (*A_lds)[264] = (unsigned short (*)[264])smraw;
    float (*C_lds)[204] = (float (*)[204])smraw;

    const int m0 = blockIdx.x * 32;
    const int tid = threadIdx.x;
    const int lane = tid & 63, wave = tid >> 6;
    const int quad = lane >> 4, l15 = lane & 15;
    const int n0 = wave * 48;

    // --- B prefetch: all 24 fragments, issued before the stage barrier ---
    bf16x8 breg[3][8];
    #pragma unroll
    for (int nt = 0; nt < 3; ++nt) {
        const unsigned short* wb = Woa_bf + (size_t)(n0 + nt*16 + l15)*DIM + quad*8;
        #pragma unroll
        for (int kc = 0; kc < 8; ++kc)
            breg[nt][kc] = *(const bf16x8*)(wb + kc*32);
    }

    // --- A stage: coalesced f32 loads, add, cvt -> LDS ---
    {
        const int row = tid >> 3;       // 0..31
        const int c8  = tid & 7;
        const float* qb = Qr + (size_t)(m0 + row)*DIM;
        const float* pb = Pe + (size_t)(m0 + row)*DIM;
        #pragma unroll
        for (int j = 0; j < 8; ++j) {
            const int col = c8*4 + j*32;
            const float4 x = *(const float4*)(qb + col);
            const float4 y = *(const float4*)(pb + col);
            ushort4 pk;
            pk.x = f2bf(x.x+y.x); pk.y = f2bf(x.y+y.y);
            pk.z = f2bf(x.z+y.z); pk.w = f2bf(x.w+y.w);
            *(ushort4*)&A_lds[row][col] = pk;
        }
    }
    __syncthreads();

    // --- K loop: LDS reads + MFMA only ---
    f32x4 acc[2][3] = {};
    #pragma unroll
    for (int kc = 0; kc < 8; ++kc) {
        const int kk = kc*32 + quad*8;
        const bf16x8 a0 = *(const bf16x8*)&A_lds[l15][kk];
        const bf16x8 a1 = *(const bf16x8*)&A_lds[16 + l15][kk];
        #pragma unroll
        for (int nt = 0; nt < 3; ++nt) {
            acc[0][nt] = __builtin_amdgcn_mfma_f32_16x16x32_bf16(a0, breg[nt][kc], acc[0][nt], 0,0,0);
            acc[1][nt] = __builtin_amdgcn_mfma_f32_16x16x32_bf16(a1, breg[nt][kc], acc[1][nt], 0,0,0);
        }
    }

    // --- epilogue: acc(+bias) -> LDS, softmax on attn cols, contiguous stores
    __syncthreads();   // all A_lds reads done before overwrite
    #pragma unroll
    for (int nt = 0; nt < 3; ++nt) {
        const int col = n0 + nt*16 + l15;
        const float bias = (col < 128) ? boff[col] : battn[col-128];
        #pragma unroll
        for (int mt = 0; mt < 2; ++mt) {
            #pragma unroll
            for (int r = 0; r < 4; ++r)
                C_lds[mt*16 + quad*4 + r][col] = acc[mt][nt][r] + bias;
        }
    }
    __syncthreads();
    // softmax: thread (row = tid>>3, h = tid&7) over 8 contiguous logits
    {
        float* a = &C_lds[tid>>3][128 + (tid&7)*8];
        float lg[8];
        float mx = -1e30f;
        #pragma unroll
        for (int p = 0; p < 8; ++p) { lg[p] = a[p]; mx = fmaxf(mx, lg[p]); }
        float ssum = 0.f;
        #pragma unroll
        for (int p = 0; p < 8; ++p) { lg[p] = __expf(lg[p]-mx); ssum += lg[p]; }
        const float inv = 1.f/ssum;
        #pragma unroll
        for (int p = 0; p < 8; ++p) a[p] = lg[p]*inv;
    }
    __syncthreads();
    // off: 32 rows x 128 f32 = 1024 float4, 4/thread, lane-contiguous
    #pragma unroll
    for (int i = 0; i < 4; ++i) {
        const int idx = i*256 + tid;
        const int row = idx >> 5, c4 = (idx & 31)*4;
        *(float4*)(off_ws + ((size_t)(m0+row))*128 + c4) = *(float4*)&C_lds[row][c4];
    }
    // attw (probabilities): 32 rows x 64 f32 = 512 float4, 2/thread
    #pragma unroll
    for (int i = 0; i < 2; ++i) {
        const int idx = i*256 + tid;
        const int row = idx >> 4, c4 = (idx & 15)*4;
        *(float4*)(attw_ws + ((size_t)(m0+row))*64 + c4) = *(float4*)&C_lds[row][128 + c4];
    }
}

// ---------------------------------------------------------------------------
// K2b: sampling fused with camera reduce.  NEW vs r6: (1) attw_ws holds
// precomputed probabilities (softmax hoisted to k_offattn); (2) half-split
// partition: block = 128 threads = (8q x 8h x 2 halves), each thread owns
// 16 channels -> address/bilinear math computed 2x per (q,h) instead of 4x.
// Same gather lane-op count and L2 lines as before.  1250 blocks.
// ---------------------------------------------------------------------------
__global__ __launch_bounds__(128)
void k_sample(const unsigned short* __restrict__ value_bf,
              const float* __restrict__ off_ws, const float* __restrict__ attw_ws,
              const float* __restrict__ ref3d, const float* __restrict__ hitf,
              const float* __restrict__ scale, unsigned short* __restrict__ asum_bf)
{
    const int q0 = blockIdx.x * 8;
    const int tid = threadIdx.x;   // 0..127

    __shared__ float s_off[8][128];
    __shared__ float s_att[8][64];
    __shared__ float s_ref[8][8];
    __shared__ float s_hit[BN][8];
    __shared__ float s_scl[8];

    if (tid < 48) s_hit[tid>>3][tid&7] = hitf[(size_t)(tid>>3)*NQ + q0 + (tid&7)];
    if (tid < 8)  s_scl[tid] = scale[q0 + tid];

    const int half = tid & 1;          // channel half: 0 -> ch 0..15, 1 -> 16..31
    const int h    = (tid >> 1) & 7;
    const int ql   = tid >> 4;         // 0..7

    float acc[16];
    #pragma unroll
    for (int c = 0; c < 16; ++c) acc[c] = 0.f;

    for (int n = 0; n < BN; ++n) {
        __syncthreads();
        {
            const float4* so = (const float4*)(off_ws + ((size_t)n*NQ + q0)*128);
            ((float4*)&s_off[0][0])[tid]       = so[tid];
            ((float4*)&s_off[0][0])[tid + 128] = so[tid + 128];
            const float4* sa = (const float4*)(attw_ws + ((size_t)n*NQ + q0)*64);
            ((float4*)&s_att[0][0])[tid] = sa[tid];
            if (tid < 64)
                (&s_ref[0][0])[tid] = (ref3d + ((size_t)n*NQ + q0)*8)[tid];
        }
        __syncthreads();

        if (s_hit[n][ql] != 0.f) {
            const unsigned short* vbase =
                value_bf + (size_t)(n*HEADS + h)*HW_*HDD + half*16;

            #pragma unroll
            for (int p = 0; p < 8; ++p) {
                const int z = p & 3;
                const float wp = s_att[ql][h*8+p];   // precomputed probability
                const float ax = s_ref[ql][z*2+0]*WF_ + s_off[ql][h*16+p*2+0] - 0.5f;
                const float ay = s_ref[ql][z*2+1]*HF_ + s_off[ql][h*16+p*2+1] - 0.5f;
                const float fx = floorf(ax), fy = floorf(ay);
                const float dx = ax-fx, dy = ay-fy;
                const int x0 = (int)fx, y0 = (int)fy;
                #pragma unroll
                for (int oy = 0; oy < 2; ++oy) {
                    const int yi = y0 + oy;
                    const float wy = oy ? dy : 1.f-dy;
                    #pragma unroll
                    for (int ox = 0; ox < 2; ++ox) {
                        const int xi = x0 + ox;
                        const float wx = ox ? dx : 1.f-dx;
                        const bool valid = ((unsigned)xi < WF_) & ((unsigned)yi < HF_);
                        const float cw = valid ? wp*wy*wx : 0.f;
                        const int xc = min(max(xi, 0), WF_-1);
                        const int yc = min(max(yi, 0), HF_-1);
                        const unsigned short* vp = vbase + (size_t)(yc*WF_ + xc)*HDD;
                        const ushort8_t v0 = *(const ushort8_t*)(vp);
                        const ushort8_t v1 = *(const ushort8_t*)(vp + 8);
                        #pragma unroll
                        for (int c = 0; c < 8; ++c) {
                            acc[c]   += cw * __uint_as_float(((unsigned)v0[c]) << 16);
                            acc[8+c] += cw * __uint_as_float(((unsigned)v1[c]) << 16);
                        }
                    }
                }
            }
        }
    }

    const float sc = s_scl[ql];
    unsigned short* ob = asum_bf + ((size_t)(q0+ql))*DIM + h*HDD + half*16;
    ushort8_t o;
    #pragma unroll
    for (int c = 0; c < 8; ++c) o[c] = f2bf(acc[c]*sc);
    *(ushort8_t*)(ob) = o;
    #pragma unroll
    for (int c = 0; c < 8; ++c) o[c] = f2bf(acc[8+c]*sc);
    *(ushort8_t*)(ob + 8) = o;
}

// ---------------------------------------------------------------------------
// K3/K4: MFMA GEMM 128m x 64n: out = A_bf[m][k]·W_bf[n][k] + f(m)*bias[n].
// Writes f32 (out_f) and/or bf16 (out_b).
// ---------------------------------------------------------------------------
__global__ __launch_bounds__(256)
void k_gemm_mfma(const unsigned short* __restrict__ A_bf,
                 const unsigned short* __restrict__ W_bf,
                 const float* __restrict__ bias, const float* __restrict__ rowscale,
                 float* __restrict__ out_f, unsigned short* __restrict__ out_b, int M)
{
    __shared__ unsigned short As[128][72];
    __shared__ unsigned short Bs[64][72];
    const int m0 = blockIdx.x * 128;
    const int j0 = blockIdx.y * 64;
    const int tid = threadIdx.x;
    const int lane = tid & 63, wave = tid >> 6;
    const int quad = lane >> 4, l15 = lane & 15;
    f32x4 acc[2][4] = {};

    for (int k0 = 0; k0 < DIM; k0 += 64) {
        #pragma unroll
        for (int i = 0; i < 4; ++i) {
            const int row = (tid>>3) + i*32;
            const int k8 = (tid&7)*8;
            ushort8_t v = {0,0,0,0,0,0,0,0};
            if (m0 + row < M)
                v = *(const ushort8_t*)(A_bf + (size_t)(m0+row)*DIM + k0 + k8);
            *(ushort8_t*)&As[row][k8] = v;
        }
        #pragma unroll
        for (int i = 0; i < 2; ++i) {
            const int row = (tid>>3) + i*32;
            const int k8 = (tid&7)*8;
            *(ushort8_t*)&Bs[row][k8] = *(const ushort8_t*)(W_bf + (size_t)(j0+row)*DIM + k0 + k8);
        }
        __syncthreads();
        #pragma unroll
        for (int s = 0; s < 2; ++s) {
            const int kf = s*32 + quad*8;
            bf16x8 a[2], b[4];
            #pragma unroll
            for (int mt = 0; mt < 2; ++mt)
                a[mt] = *(const bf16x8*)&As[(wave*2+mt)*16 + l15][kf];
            #pragma unroll
            for (int nt = 0; nt < 4; ++nt)
                b[nt] = *(const bf16x8*)&Bs[nt*16 + l15][kf];
            #pragma unroll
            for (int mt = 0; mt < 2; ++mt)
                #pragma unroll
                for (int nt = 0; nt < 4; ++nt)
                    acc[mt][nt] = __builtin_amdgcn_mfma_f32_16x16x32_bf16(a[mt], b[nt], acc[mt][nt], 0,0,0);
        }
        __syncthreads();
    }
    #pragma unroll
    for (int nt = 0; nt < 4; ++nt) {
        const int j = j0 + nt*16 + l15;
        const float bj = bias[j];
        #pragma unroll
        for (int mt = 0; mt < 2; ++mt) {
            #pragma unroll
            for (int r = 0; r < 4; ++r) {
                const int m = m0 + (wave*2+mt)*16 + quad*4 + r;
                if (m >= M) continue;
                const float f = rowscale ? rowscale[m] : 1.f;
                const float v = acc[mt][nt][r] + f*bj;
                if (out_f) out_f[(size_t)m*DIM + j] = v;
                if (out_b) out_b[(size_t)m*DIM + j] = f2bf(v);
            }
        }
    }
}

// ---------------------------------------------------------------------------
extern "C" void kernel_launch(void* const* d_in, const int* in_sizes, int n_in,
                              void* d_out, int out_size, void* d_ws, size_t ws_size,
                              hipStream_t stream)
{
    const float* queries = (const float*)d_in[0];
    const float* pos_emb = (const float*)d_in[1];
    const float* lvl_emb = (const float*)d_in[2];
    const float* cam_emb = (const float*)d_in[3];
    const float* features= (const float*)d_in[4];
    const float* ref3d   = (const float*)d_in[5];
    const int*   bev     = (const int*)d_in[6];
    const float* Wv = (const float*)d_in[7];
    const float* bv = (const float*)d_in[8];
    const float* Wo = (const float*)d_in[9];
    const float* bo = (const float*)d_in[10];
    const float* Wa = (const float*)d_in[11];
    const float* ba = (const float*)d_in[12];
    const float* Wi = (const float*)d_in[13];
    const float* bi = (const float*)d_in[14];
    const float* Wz = (const float*)d_in[15];
    const float* bz = (const float*)d_in[16];
    float* out = (float*)d_out;

    char* ws = (char*)d_ws;
    size_t o = 0;
    auto alloc = [&](size_t bytes) { char* p = ws + o; o += (bytes + 255) & ~size_t(255); return p; };
    unsigned short* value_bf = (unsigned short*)alloc((size_t)BN*HEADS*HW_*HDD*2);  // 8.65 MB
    unsigned short* featT    = (unsigned short*)alloc((size_t)BN*HW_*DIM*2);        // 8.65 MB
    float* off_ws   = (float*)alloc((size_t)MTOT*128*4);                            // 30.7 MB
    float* attw_ws  = (float*)alloc((size_t)MTOT*64*4);                             // 15.4 MB
    unsigned short* asum_bf  = (unsigned short*)alloc((size_t)NQ*DIM*2);            // 5.1 MB
    unsigned short* slots_bf = (unsigned short*)alloc((size_t)NQ*DIM*2);            // 5.1 MB
    unsigned short* Wv_bf  = (unsigned short*)alloc(65536*2);
    unsigned short* Woa_bf = (unsigned short*)alloc(49152*2);
    unsigned short* Wi_bf  = (unsigned short*)alloc(65536*2);
    unsigned short* Wz_bf  = (unsigned short*)alloc(65536*2);
    float* hitf   = (float*)alloc((size_t)BN*NQ*4);
    float* scalev = (float*)alloc(NQ*4);
    float* biasf  = (float*)alloc(NQ*4);
    float* ebias  = (float*)alloc(BN*DIM*4);
    // total ~74 MB

    k_wcvt  <<<64, 256, 0, stream>>>(Wv, Wo, Wa, Wi, Wz, Wv_bf, Woa_bf, Wi_bf, Wz_bf);
    k_ebias <<<BN, 256, 0, stream>>>(lvl_emb, cam_emb, Wv, bv, ebias);
    k_mask  <<<(NQ+255)/256, 256, 0, stream>>>(bev, hitf, scalev, biasf);
    k_feat  <<<dim3(HW_/64, DIM/64, BN), 256, 0, stream>>>(features, featT);
    k_value_mfma<<<dim3(HW_/128, DIM/64, BN), 256, 0, stream>>>(featT, Wv_bf, ebias, value_bf);
    k_offattn<<<MTOT/32, 256, 0, stream>>>(queries, pos_emb, Woa_bf, bo, ba, off_ws, attw_ws);
    k_sample <<<NQ/8, 128, 0, stream>>>(value_bf, off_ws, attw_ws, ref3d, hitf, scalev, asum_bf);
    k_gemm_mfma<<<dim3((NQ+127)/128, DIM/64), 256, 0, stream>>>(asum_bf, Wi_bf, bi, biasf, nullptr, slots_bf, NQ);
    k_gemm_mfma<<<dim3((NQ+127)/128, DIM/64), 256, 0, stream>>>(slots_bf, Wz_bf, bz, nullptr, out, nullptr, NQ);
}

// Round 8
// 342.569 us; speedup vs baseline: 1.1146x; 1.1146x over previous
//
#include <hip/hip_runtime.h>
#include <hip/hip_bf16.h>

#define BN     6
#define NQ     10000
#define DIM    256
#define HEADS  8
#define HDD    32
#define HF_    32
#define WF_    88
#define HW_    (HF_*WF_)     /* 2816 */
#define MTOT   (BN*NQ)       /* 60000 */

typedef __attribute__((ext_vector_type(8))) unsigned short ushort8_t;
typedef __attribute__((ext_vector_type(8))) short bf16x8;
typedef __attribute__((ext_vector_type(4))) float f32x4;

static __device__ inline unsigned short f2bf(float x) {
    __hip_bfloat16 b = __float2bfloat16(x);
    return *(unsigned short*)&b;
}

// ---------------------------------------------------------------------------
// K_wcvt: f32 weights -> bf16 copies. Wv(65536), Wo(32768)+Wa(16384)->Woa,
// Wi(65536), Wz(65536).
// ---------------------------------------------------------------------------
__global__ __launch_bounds__(256)
void k_wcvt(const float* __restrict__ Wv, const float* __restrict__ Wo,
            const float* __restrict__ Wa, const float* __restrict__ Wi,
            const float* __restrict__ Wz,
            unsigned short* __restrict__ Wv_bf, unsigned short* __restrict__ Woa_bf,
            unsigned short* __restrict__ Wi_bf, unsigned short* __restrict__ Wz_bf)
{
    const int i4 = (blockIdx.x*256 + threadIdx.x) * 4;
    if (i4 < 65536) {
        float4 v;
        ushort4 p;
        v = *(const float4*)(Wv+i4); p.x=f2bf(v.x);p.y=f2bf(v.y);p.z=f2bf(v.z);p.w=f2bf(v.w);
        *(ushort4*)(Wv_bf+i4) = p;
        v = *(const float4*)(Wi+i4); p.x=f2bf(v.x);p.y=f2bf(v.y);p.z=f2bf(v.z);p.w=f2bf(v.w);
        *(ushort4*)(Wi_bf+i4) = p;
        v = *(const float4*)(Wz+i4); p.x=f2bf(v.x);p.y=f2bf(v.y);p.z=f2bf(v.z);p.w=f2bf(v.w);
        *(ushort4*)(Wz_bf+i4) = p;
    }
    if (i4 < 32768) {
        float4 v = *(const float4*)(Wo+i4);
        ushort4 p; p.x=f2bf(v.x);p.y=f2bf(v.y);p.z=f2bf(v.z);p.w=f2bf(v.w);
        *(ushort4*)(Woa_bf+i4) = p;
    }
    if (i4 < 16384) {
        float4 v = *(const float4*)(Wa+i4);
        ushort4 p; p.x=f2bf(v.x);p.y=f2bf(v.y);p.z=f2bf(v.z);p.w=f2bf(v.w);
        *(ushort4*)(Woa_bf+32768+i4) = p;
    }
}

// ---------------------------------------------------------------------------
// K0: ebias[n][j] = sum_d (lvl[d]+cam[n][d]) * W_value[j][d] + b_value[j]
// ---------------------------------------------------------------------------
__global__ __launch_bounds__(256)
void k_ebias(const float* __restrict__ lvl, const float* __restrict__ cam,
             const float* __restrict__ Wv, const float* __restrict__ bv,
             float* __restrict__ ebias)
{
    const int n = blockIdx.x;
    const int j = threadIdx.x;
    __shared__ float e[DIM];
    e[j] = lvl[j] + cam[n*DIM + j];
    __syncthreads();
    const float* w = Wv + (size_t)j*DIM;
    float s = bv[j];
    for (int d = 0; d < DIM; ++d) s += e[d]*w[d];
    ebias[n*DIM + j] = s;
}

// ---------------------------------------------------------------------------
// K_mask: per-q hit flags, count scale, bias gate.
// ---------------------------------------------------------------------------
__global__ __launch_bounds__(256)
void k_mask(const int* __restrict__ bev, float* __restrict__ hitf,
            float* __restrict__ scale, float* __restrict__ biasf)
{
    const int q = blockIdx.x*256 + threadIdx.x;
    if (q >= NQ) return;
    float cnt = 0.f;
    #pragma unroll
    for (int n = 0; n < BN; ++n) {
        int hit = 0;
        #pragma unroll
        for (int z = 0; z < 4; ++z)
            hit |= (bev[(((size_t)n*NQ + q)*4 + z)*2] != 0);
        hitf[(size_t)n*NQ + q] = (float)hit;
        cnt += (float)hit;
    }
    biasf[q] = (cnt > 0.f) ? 1.f : 0.f;
    scale[q] = 1.f / fmaxf(cnt, 1.f);
}

// ---------------------------------------------------------------------------
// K_feat: transpose feat[cam][256 d][2816 p] f32 -> featT[cam][p][d] bf16.
// 64x64 tiles through LDS.
// ---------------------------------------------------------------------------
__global__ __launch_bounds__(256)
void k_feat(const float* __restrict__ feat, unsigned short* __restrict__ featT)
{
    __shared__ float Tf[64][68];
    const int cam = blockIdx.z;
    const int d0 = blockIdx.y * 64;
    const int p0 = blockIdx.x * 64;
    const int tid = threadIdx.x;
    #pragma unroll
    for (int i = 0; i < 4; ++i) {
        const int d = (tid>>4) + i*16;
        const int p4 = (tid&15)*4;
        *(float4*)&Tf[d][p4] = *(const float4*)(feat + ((size_t)cam*DIM + d0 + d)*HW_ + p0 + p4);
    }
    __syncthreads();
    const int p = tid>>2, dq = tid&3;
    unsigned short* ob = featT + ((size_t)cam*HW_ + p0 + p)*DIM + d0;
    #pragma unroll
    for (int i = 0; i < 4; ++i) {
        const int d4 = dq*4 + i*16;
        ushort4 pk;
        pk.x = f2bf(Tf[d4+0][p]); pk.y = f2bf(Tf[d4+1][p]);
        pk.z = f2bf(Tf[d4+2][p]); pk.w = f2bf(Tf[d4+3][p]);
        *(ushort4*)(ob + d4) = pk;
    }
}

// ---------------------------------------------------------------------------
// K1: value GEMM via MFMA.  D[p][c] = featT[p][k] · Wv_bf[c][k] + ebias[c].
// Block tile 128p x 64c, K-chunks of 64.  value_bf[(cam*8+h)*HW+p][c&31].
// ---------------------------------------------------------------------------
__global__ __launch_bounds__(256)
void k_value_mfma(const unsigned short* __restrict__ featT,
                  const unsigned short* __restrict__ Wv_bf,
                  const float* __restrict__ ebias,
                  unsigned short* __restrict__ value_bf)
{
    __shared__ unsigned short Ap[128][72];
    __shared__ unsigned short Bc[64][72];
    const int cam = blockIdx.z;
    const int p0 = blockIdx.x * 128;
    const int c0 = blockIdx.y * 64;
    const int tid = threadIdx.x;
    const int lane = tid & 63, wave = tid >> 6;
    const int quad = lane >> 4, l15 = lane & 15;
    f32x4 acc[2][4] = {};
    const unsigned short* fbase = featT + ((size_t)cam*HW_ + p0)*DIM;

    for (int k0 = 0; k0 < DIM; k0 += 64) {
        #pragma unroll
        for (int i = 0; i < 4; ++i) {
            const int row = (tid>>3) + i*32;
            const int k8 = (tid&7)*8;
            *(ushort8_t*)&Ap[row][k8] = *(const ushort8_t*)(fbase + (size_t)row*DIM + k0 + k8);
        }
        #pragma unroll
        for (int i = 0; i < 2; ++i) {
            const int row = (tid>>3) + i*32;
            const int k8 = (tid&7)*8;
            *(ushort8_t*)&Bc[row][k8] = *(const ushort8_t*)(Wv_bf + (size_t)(c0+row)*DIM + k0 + k8);
        }
        __syncthreads();
        #pragma unroll
        for (int s = 0; s < 2; ++s) {
            const int kf = s*32 + quad*8;
            bf16x8 a[2], b[4];
            #pragma unroll
            for (int mt = 0; mt < 2; ++mt)
                a[mt] = *(const bf16x8*)&Ap[(wave*2+mt)*16 + l15][kf];
            #pragma unroll
            for (int nt = 0; nt < 4; ++nt)
                b[nt] = *(const bf16x8*)&Bc[nt*16 + l15][kf];
            #pragma unroll
            for (int mt = 0; mt < 2; ++mt)
                #pragma unroll
                for (int nt = 0; nt < 4; ++nt)
                    acc[mt][nt] = __builtin_amdgcn_mfma_f32_16x16x32_bf16(a[mt], b[nt], acc[mt][nt], 0,0,0);
        }
        __syncthreads();
    }
    #pragma unroll
    for (int nt = 0; nt < 4; ++nt) {
        const int c = c0 + nt*16 + l15;
        const float eb = ebias[cam*DIM + c];
        const int h = c >> 5, cc = c & 31;
        unsigned short* vb = value_bf + (size_t)(cam*HEADS + h)*HW_*HDD + cc;
        #pragma unroll
        for (int mt = 0; mt < 2; ++mt)
            #pragma unroll
            for (int r = 0; r < 4; ++r) {
                const int p = p0 + (wave*2+mt)*16 + quad*4 + r;
                vb[(size_t)p*HDD] = f2bf(acc[mt][nt][r] + eb);
            }
    }
}

// ---------------------------------------------------------------------------
// K2a: off/attn GEMM with fused Qr+Pe add/convert, B reg-prefetch, LDS
// epilogue with contiguous stores, and softmax applied in the epilogue
// (attw_ws stores PROBABILITIES).
// ---------------------------------------------------------------------------
__global__ __launch_bounds__(256, 3)
void k_offattn(const float* __restrict__ Qr, const float* __restrict__ Pe,
               const unsigned short* __restrict__ Woa_bf,
               const float* __restrict__ boff, const float* __restrict__ battn,
               float* __restrict__ off_ws, float* __restrict__ attw_ws)
{
    __shared__ char smraw[32*204*4];
    unsigned short (*A_lds)[264] = (unsigned short (*)[264])smraw;
    float (*C_lds)[204] = (float (*)[204])smraw;

    const int m0 = blockIdx.x * 32;
    const int tid = threadIdx.x;
    const int lane = tid & 63, wave = tid >> 6;
    const int quad = lane >> 4, l15 = lane & 15;
    const int n0 = wave * 48;

    // --- B prefetch: all 24 fragments, issued before the stage barrier ---
    bf16x8 breg[3][8];
    #pragma unroll
    for (int nt = 0; nt < 3; ++nt) {
        const unsigned short* wb = Woa_bf + (size_t)(n0 + nt*16 + l15)*DIM + quad*8;
        #pragma unroll
        for (int kc = 0; kc < 8; ++kc)
            breg[nt][kc] = *(const bf16x8*)(wb + kc*32);
    }

    // --- A stage: coalesced f32 loads, add, cvt -> LDS ---
    {
        const int row = tid >> 3;       // 0..31
        const int c8  = tid & 7;
        const float* qb = Qr + (size_t)(m0 + row)*DIM;
        const float* pb = Pe + (size_t)(m0 + row)*DIM;
        #pragma unroll
        for (int j = 0; j < 8; ++j) {
            const int col = c8*4 + j*32;
            const float4 x = *(const float4*)(qb + col);
            const float4 y = *(const float4*)(pb + col);
            ushort4 pk;
            pk.x = f2bf(x.x+y.x); pk.y = f2bf(x.y+y.y);
            pk.z = f2bf(x.z+y.z); pk.w = f2bf(x.w+y.w);
            *(ushort4*)&A_lds[row][col] = pk;
        }
    }
    __syncthreads();

    // --- K loop: LDS reads + MFMA only ---
    f32x4 acc[2][3] = {};
    #pragma unroll
    for (int kc = 0; kc < 8; ++kc) {
        const int kk = kc*32 + quad*8;
        const bf16x8 a0 = *(const bf16x8*)&A_lds[l15][kk];
        const bf16x8 a1 = *(const bf16x8*)&A_lds[16 + l15][kk];
        #pragma unroll
        for (int nt = 0; nt < 3; ++nt) {
            acc[0][nt] = __builtin_amdgcn_mfma_f32_16x16x32_bf16(a0, breg[nt][kc], acc[0][nt], 0,0,0);
            acc[1][nt] = __builtin_amdgcn_mfma_f32_16x16x32_bf16(a1, breg[nt][kc], acc[1][nt], 0,0,0);
        }
    }

    // --- epilogue: acc(+bias) -> LDS, softmax on attn cols, contiguous stores
    __syncthreads();   // all A_lds reads done before overwrite
    #pragma unroll
    for (int nt = 0; nt < 3; ++nt) {
        const int col = n0 + nt*16 + l15;
        const float bias = (col < 128) ? boff[col] : battn[col-128];
        #pragma unroll
        for (int mt = 0; mt < 2; ++mt) {
            #pragma unroll
            for (int r = 0; r < 4; ++r)
                C_lds[mt*16 + quad*4 + r][col] = acc[mt][nt][r] + bias;
        }
    }
    __syncthreads();
    // softmax: thread (row = tid>>3, h = tid&7) over 8 contiguous logits
    {
        float* a = &C_lds[tid>>3][128 + (tid&7)*8];
        float lg[8];
        float mx = -1e30f;
        #pragma unroll
        for (int p = 0; p < 8; ++p) { lg[p] = a[p]; mx = fmaxf(mx, lg[p]); }
        float ssum = 0.f;
        #pragma unroll
        for (int p = 0; p < 8; ++p) { lg[p] = __expf(lg[p]-mx); ssum += lg[p]; }
        const float inv = 1.f/ssum;
        #pragma unroll
        for (int p = 0; p < 8; ++p) a[p] = lg[p]*inv;
    }
    __syncthreads();
    // off: 32 rows x 128 f32 = 1024 float4, 4/thread, lane-contiguous
    #pragma unroll
    for (int i = 0; i < 4; ++i) {
        const int idx = i*256 + tid;
        const int row = idx >> 5, c4 = (idx & 31)*4;
        *(float4*)(off_ws + ((size_t)(m0+row))*128 + c4) = *(float4*)&C_lds[row][c4];
    }
    // attw (probabilities): 32 rows x 64 f32 = 512 float4, 2/thread
    #pragma unroll
    for (int i = 0; i < 2; ++i) {
        const int idx = i*256 + tid;
        const int row = idx >> 4, c4 = (idx & 15)*4;
        *(float4*)(attw_ws + ((size_t)(m0+row))*64 + c4) = *(float4*)&C_lds[row][128 + c4];
    }
}

// ---------------------------------------------------------------------------
// K2b: sampling fused with camera reduce.  Round-5/6 quarter-split structure
// (256 thr, 8q/block, acc[8], VGPR~72 -- MUST stay at this register budget;
// r3/r7 widened variants blew VGPR and collapsed occupancy).  Only delta vs
// r6: attw_ws already holds probabilities -> no softmax here.
// ---------------------------------------------------------------------------
__global__ __launch_bounds__(256)
void k_sample(const unsigned short* __restrict__ value_bf,
              const float* __restrict__ off_ws, const float* __restrict__ attw_ws,
              const float* __restrict__ ref3d, const float* __restrict__ hitf,
              const float* __restrict__ scale, unsigned short* __restrict__ asum_bf)
{
    const int q0 = blockIdx.x * 8;
    const int tid = threadIdx.x;

    __shared__ float s_off[8][128];
    __shared__ float s_att[8][64];
    __shared__ float s_ref[8][8];
    __shared__ float s_hit[BN][8];
    __shared__ float s_scl[8];

    if (tid < 48) s_hit[tid>>3][tid&7] = hitf[(size_t)(tid>>3)*NQ + q0 + (tid&7)];
    if (tid < 8)  s_scl[tid] = scale[q0 + tid];

    const int quarter = tid & 3;
    const int h  = (tid >> 2) & 7;
    const int ql = tid >> 5;

    float acc[8];
    #pragma unroll
    for (int c = 0; c < 8; ++c) acc[c] = 0.f;

    for (int n = 0; n < BN; ++n) {
        __syncthreads();
        {
            const float4* so = (const float4*)(off_ws + ((size_t)n*NQ + q0)*128);
            ((float4*)&s_off[0][0])[tid] = so[tid];
            const float2* sa = (const float2*)(attw_ws + ((size_t)n*NQ + q0)*64);
            ((float2*)&s_att[0][0])[tid] = sa[tid];
            if (tid < 64)
                (&s_ref[0][0])[tid] = (ref3d + ((size_t)n*NQ + q0)*8)[tid];
        }
        __syncthreads();

        if (s_hit[n][ql] != 0.f) {
            const unsigned short* vbase =
                value_bf + (size_t)(n*HEADS + h)*HW_*HDD + quarter*8;

            #pragma unroll
            for (int p = 0; p < 8; ++p) {
                const int z = p & 3;
                const float wp = s_att[ql][h*8+p];   // precomputed probability
                const float ax = s_ref[ql][z*2+0]*WF_ + s_off[ql][h*16+p*2+0] - 0.5f;
                const float ay = s_ref[ql][z*2+1]*HF_ + s_off[ql][h*16+p*2+1] - 0.5f;
                const float fx = floorf(ax), fy = floorf(ay);
                const float dx = ax-fx, dy = ay-fy;
                const int x0 = (int)fx, y0 = (int)fy;
                #pragma unroll
                for (int oy = 0; oy < 2; ++oy) {
                    const int yi = y0 + oy;
                    const float wy = oy ? dy : 1.f-dy;
                    #pragma unroll
                    for (int ox = 0; ox < 2; ++ox) {
                        const int xi = x0 + ox;
                        const float wx = ox ? dx : 1.f-dx;
                        const bool valid = ((unsigned)xi < WF_) & ((unsigned)yi < HF_);
                        const float cw = valid ? wp*wy*wx : 0.f;
                        const int xc = min(max(xi, 0), WF_-1);
                        const int yc = min(max(yi, 0), HF_-1);
                        const ushort8_t v = *(const ushort8_t*)(vbase + (size_t)(yc*WF_ + xc)*HDD);
                        #pragma unroll
                        for (int c = 0; c < 8; ++c)
                            acc[c] += cw * __uint_as_float(((unsigned)v[c]) << 16);
                    }
                }
            }
        }
    }

    const float sc = s_scl[ql];
    ushort8_t o;
    #pragma unroll
    for (int c = 0; c < 8; ++c) o[c] = f2bf(acc[c]*sc);
    *(ushort8_t*)(asum_bf + ((size_t)(q0+ql))*DIM + h*HDD + quarter*8) = o;
}

// ---------------------------------------------------------------------------
// K3/K4: MFMA GEMM 128m x 64n: out = A_bf[m][k]·W_bf[n][k] + f(m)*bias[n].
// Writes f32 (out_f) and/or bf16 (out_b).
// ---------------------------------------------------------------------------
__global__ __launch_bounds__(256)
void k_gemm_mfma(const unsigned short* __restrict__ A_bf,
                 const unsigned short* __restrict__ W_bf,
                 const float* __restrict__ bias, const float* __restrict__ rowscale,
                 float* __restrict__ out_f, unsigned short* __restrict__ out_b, int M)
{
    __shared__ unsigned short As[128][72];
    __shared__ unsigned short Bs[64][72];
    const int m0 = blockIdx.x * 128;
    const int j0 = blockIdx.y * 64;
    const int tid = threadIdx.x;
    const int lane = tid & 63, wave = tid >> 6;
    const int quad = lane >> 4, l15 = lane & 15;
    f32x4 acc[2][4] = {};

    for (int k0 = 0; k0 < DIM; k0 += 64) {
        #pragma unroll
        for (int i = 0; i < 4; ++i) {
            const int row = (tid>>3) + i*32;
            const int k8 = (tid&7)*8;
            ushort8_t v = {0,0,0,0,0,0,0,0};
            if (m0 + row < M)
                v = *(const ushort8_t*)(A_bf + (size_t)(m0+row)*DIM + k0 + k8);
            *(ushort8_t*)&As[row][k8] = v;
        }
        #pragma unroll
        for (int i = 0; i < 2; ++i) {
            const int row = (tid>>3) + i*32;
            const int k8 = (tid&7)*8;
            *(ushort8_t*)&Bs[row][k8] = *(const ushort8_t*)(W_bf + (size_t)(j0+row)*DIM + k0 + k8);
        }
        __syncthreads();
        #pragma unroll
        for (int s = 0; s < 2; ++s) {
            const int kf = s*32 + quad*8;
            bf16x8 a[2], b[4];
            #pragma unroll
            for (int mt = 0; mt < 2; ++mt)
                a[mt] = *(const bf16x8*)&As[(wave*2+mt)*16 + l15][kf];
            #pragma unroll
            for (int nt = 0; nt < 4; ++nt)
                b[nt] = *(const bf16x8*)&Bs[nt*16 + l15][kf];
            #pragma unroll
            for (int mt = 0; mt < 2; ++mt)
                #pragma unroll
                for (int nt = 0; nt < 4; ++nt)
                    acc[mt][nt] = __builtin_amdgcn_mfma_f32_16x16x32_bf16(a[mt], b[nt], acc[mt][nt], 0,0,0);
        }
        __syncthreads();
    }
    #pragma unroll
    for (int nt = 0; nt < 4; ++nt) {
        const int j = j0 + nt*16 + l15;
        const float bj = bias[j];
        #pragma unroll
        for (int mt = 0; mt < 2; ++mt) {
            #pragma unroll
            for (int r = 0; r < 4; ++r) {
                const int m = m0 + (wave*2+mt)*16 + quad*4 + r;
                if (m >= M) continue;
                const float f = rowscale ? rowscale[m] : 1.f;
                const float v = acc[mt][nt][r] + f*bj;
                if (out_f) out_f[(size_t)m*DIM + j] = v;
                if (out_b) out_b[(size_t)m*DIM + j] = f2bf(v);
            }
        }
    }
}

// ---------------------------------------------------------------------------
extern "C" void kernel_launch(void* const* d_in, const int* in_sizes, int n_in,
                              void* d_out, int out_size, void* d_ws, size_t ws_size,
                              hipStream_t stream)
{
    const float* queries = (const float*)d_in[0];
    const float* pos_emb = (const float*)d_in[1];
    const float* lvl_emb = (const float*)d_in[2];
    const float* cam_emb = (const float*)d_in[3];
    const float* features= (const float*)d_in[4];
    const float* ref3d   = (const float*)d_in[5];
    const int*   bev     = (const int*)d_in[6];
    const float* Wv = (const float*)d_in[7];
    const float* bv = (const float*)d_in[8];
    const float* Wo = (const float*)d_in[9];
    const float* bo = (const float*)d_in[10];
    const float* Wa = (const float*)d_in[11];
    const float* ba = (const float*)d_in[12];
    const float* Wi = (const float*)d_in[13];
    const float* bi = (const float*)d_in[14];
    const float* Wz = (const float*)d_in[15];
    const float* bz = (const float*)d_in[16];
    float* out = (float*)d_out;

    char* ws = (char*)d_ws;
    size_t o = 0;
    auto alloc = [&](size_t bytes) { char* p = ws + o; o += (bytes + 255) & ~size_t(255); return p; };
    unsigned short* value_bf = (unsigned short*)alloc((size_t)BN*HEADS*HW_*HDD*2);  // 8.65 MB
    unsigned short* featT    = (unsigned short*)alloc((size_t)BN*HW_*DIM*2);        // 8.65 MB
    float* off_ws   = (float*)alloc((size_t)MTOT*128*4);                            // 30.7 MB
    float* attw_ws  = (float*)alloc((size_t)MTOT*64*4);                             // 15.4 MB
    unsigned short* asum_bf  = (unsigned short*)alloc((size_t)NQ*DIM*2);            // 5.1 MB
    unsigned short* slots_bf = (unsigned short*)alloc((size_t)NQ*DIM*2);            // 5.1 MB
    unsigned short* Wv_bf  = (unsigned short*)alloc(65536*2);
    unsigned short* Woa_bf = (unsigned short*)alloc(49152*2);
    unsigned short* Wi_bf  = (unsigned short*)alloc(65536*2);
    unsigned short* Wz_bf  = (unsigned short*)alloc(65536*2);
    float* hitf   = (float*)alloc((size_t)BN*NQ*4);
    float* scalev = (float*)alloc(NQ*4);
    float* biasf  = (float*)alloc(NQ*4);
    float* ebias  = (float*)alloc(BN*DIM*4);
    // total ~74 MB

    k_wcvt  <<<64, 256, 0, stream>>>(Wv, Wo, Wa, Wi, Wz, Wv_bf, Woa_bf, Wi_bf, Wz_bf);
    k_ebias <<<BN, 256, 0, stream>>>(lvl_emb, cam_emb, Wv, bv, ebias);
    k_mask  <<<(NQ+255)/256, 256, 0, stream>>>(bev, hitf, scalev, biasf);
    k_feat  <<<dim3(HW_/64, DIM/64, BN), 256, 0, stream>>>(features, featT);
    k_value_mfma<<<dim3(HW_/128, DIM/64, BN), 256, 0, stream>>>(featT, Wv_bf, ebias, value_bf);
    k_offattn<<<MTOT/32, 256, 0, stream>>>(queries, pos_emb, Woa_bf, bo, ba, off_ws, attw_ws);
    k_sample <<<NQ/8, 256, 0, stream>>>(value_bf, off_ws, attw_ws, ref3d, hitf, scalev, asum_bf);
    k_gemm_mfma<<<dim3((NQ+127)/128, DIM/64), 256, 0, stream>>>(asum_bf, Wi_bf, bi, biasf, nullptr, slots_bf, NQ);
    k_gemm_mfma<<<dim3((NQ+127)/128, DIM/64), 256, 0, stream>>>(slots_bf, Wz_bf, bz, nullptr, out, nullptr, NQ);
}

// Round 9
// 325.839 us; speedup vs baseline: 1.1718x; 1.0513x over previous
//
#include <hip/hip_runtime.h>
#include <hip/hip_bf16.h>

#define BN     6
#define NQ     10000
#define DIM    256
#define HEADS  8
#define HDD    32
#define HF_    32
#define WF_    88
#define HW_    (HF_*WF_)     /* 2816 */
#define MTOT   (BN*NQ)       /* 60000 */

typedef __attribute__((ext_vector_type(8))) unsigned short ushort8_t;
typedef __attribute__((ext_vector_type(8))) short bf16x8;
typedef __attribute__((ext_vector_type(4))) float f32x4;

static __device__ inline unsigned short f2bf(float x) {
    __hip_bfloat16 b = __float2bfloat16(x);
    return *(unsigned short*)&b;
}

// ---------------------------------------------------------------------------
// K_prep: merged weight-convert (blocks 0..63), ebias (64..69), mask (70..109).
// Replaces k_wcvt + k_ebias + k_mask (3 launches -> 1).
// ---------------------------------------------------------------------------
__global__ __launch_bounds__(256)
void k_prep(const float* __restrict__ Wv, const float* __restrict__ Wo,
            const float* __restrict__ Wa, const float* __restrict__ Wi,
            const float* __restrict__ Wz,
            const float* __restrict__ lvl, const float* __restrict__ cam,
            const float* __restrict__ bv, const int* __restrict__ bev,
            unsigned short* __restrict__ Wv_bf, unsigned short* __restrict__ Woa_bf,
            unsigned short* __restrict__ Wi_bf, unsigned short* __restrict__ Wz_bf,
            float* __restrict__ ebias, float* __restrict__ hitf,
            float* __restrict__ scale, float* __restrict__ biasf)
{
    const int b = blockIdx.x;
    const int tid = threadIdx.x;
    if (b < 64) {
        const int i4 = (b*256 + tid) * 4;
        if (i4 < 65536) {
            float4 v;
            ushort4 p;
            v = *(const float4*)(Wv+i4); p.x=f2bf(v.x);p.y=f2bf(v.y);p.z=f2bf(v.z);p.w=f2bf(v.w);
            *(ushort4*)(Wv_bf+i4) = p;
            v = *(const float4*)(Wi+i4); p.x=f2bf(v.x);p.y=f2bf(v.y);p.z=f2bf(v.z);p.w=f2bf(v.w);
            *(ushort4*)(Wi_bf+i4) = p;
            v = *(const float4*)(Wz+i4); p.x=f2bf(v.x);p.y=f2bf(v.y);p.z=f2bf(v.z);p.w=f2bf(v.w);
            *(ushort4*)(Wz_bf+i4) = p;
        }
        if (i4 < 32768) {
            float4 v = *(const float4*)(Wo+i4);
            ushort4 p; p.x=f2bf(v.x);p.y=f2bf(v.y);p.z=f2bf(v.z);p.w=f2bf(v.w);
            *(ushort4*)(Woa_bf+i4) = p;
        }
        if (i4 < 16384) {
            float4 v = *(const float4*)(Wa+i4);
            ushort4 p; p.x=f2bf(v.x);p.y=f2bf(v.y);p.z=f2bf(v.z);p.w=f2bf(v.w);
            *(ushort4*)(Woa_bf+32768+i4) = p;
        }
    } else if (b < 70) {
        const int n = b - 64;
        const int j = tid;
        __shared__ float e[DIM];
        e[j] = lvl[j] + cam[n*DIM + j];
        __syncthreads();
        const float* w = Wv + (size_t)j*DIM;
        float s = bv[j];
        for (int d = 0; d < DIM; ++d) s += e[d]*w[d];
        ebias[n*DIM + j] = s;
    } else {
        const int q = (b - 70)*256 + tid;
        if (q >= NQ) return;
        float cnt = 0.f;
        #pragma unroll
        for (int n = 0; n < BN; ++n) {
            int hit = 0;
            #pragma unroll
            for (int z = 0; z < 4; ++z)
                hit |= (bev[(((size_t)n*NQ + q)*4 + z)*2] != 0);
            hitf[(size_t)n*NQ + q] = (float)hit;
            cnt += (float)hit;
        }
        biasf[q] = (cnt > 0.f) ? 1.f : 0.f;
        scale[q] = 1.f / fmaxf(cnt, 1.f);
    }
}

// ---------------------------------------------------------------------------
// K_feat: transpose feat[cam][256 d][2816 p] f32 -> featT[cam][p][d] bf16.
// 64x64 tiles through LDS.
// ---------------------------------------------------------------------------
__global__ __launch_bounds__(256)
void k_feat(const float* __restrict__ feat, unsigned short* __restrict__ featT)
{
    __shared__ float Tf[64][68];
    const int cam = blockIdx.z;
    const int d0 = blockIdx.y * 64;
    const int p0 = blockIdx.x * 64;
    const int tid = threadIdx.x;
    #pragma unroll
    for (int i = 0; i < 4; ++i) {
        const int d = (tid>>4) + i*16;
        const int p4 = (tid&15)*4;
        *(float4*)&Tf[d][p4] = *(const float4*)(feat + ((size_t)cam*DIM + d0 + d)*HW_ + p0 + p4);
    }
    __syncthreads();
    const int p = tid>>2, dq = tid&3;
    unsigned short* ob = featT + ((size_t)cam*HW_ + p0 + p)*DIM + d0;
    #pragma unroll
    for (int i = 0; i < 4; ++i) {
        const int d4 = dq*4 + i*16;
        ushort4 pk;
        pk.x = f2bf(Tf[d4+0][p]); pk.y = f2bf(Tf[d4+1][p]);
        pk.z = f2bf(Tf[d4+2][p]); pk.w = f2bf(Tf[d4+3][p]);
        *(ushort4*)(ob + d4) = pk;
    }
}

// ---------------------------------------------------------------------------
// K1: value GEMM via MFMA.  D[p][c] = featT[p][k] · Wv_bf[c][k] + ebias[c].
// Block tile 128p x 64c, K-chunks of 64.  value_bf[(cam*8+h)*HW+p][c&31].
// ---------------------------------------------------------------------------
__global__ __launch_bounds__(256)
void k_value_mfma(const unsigned short* __restrict__ featT,
                  const unsigned short* __restrict__ Wv_bf,
                  const float* __restrict__ ebias,
                  unsigned short* __restrict__ value_bf)
{
    __shared__ unsigned short Ap[128][72];
    __shared__ unsigned short Bc[64][72];
    const int cam = blockIdx.z;
    const int p0 = blockIdx.x * 128;
    const int c0 = blockIdx.y * 64;
    const int tid = threadIdx.x;
    const int lane = tid & 63, wave = tid >> 6;
    const int quad = lane >> 4, l15 = lane & 15;
    f32x4 acc[2][4] = {};
    const unsigned short* fbase = featT + ((size_t)cam*HW_ + p0)*DIM;

    for (int k0 = 0; k0 < DIM; k0 += 64) {
        #pragma unroll
        for (int i = 0; i < 4; ++i) {
            const int row = (tid>>3) + i*32;
            const int k8 = (tid&7)*8;
            *(ushort8_t*)&Ap[row][k8] = *(const ushort8_t*)(fbase + (size_t)row*DIM + k0 + k8);
        }
        #pragma unroll
        for (int i = 0; i < 2; ++i) {
            const int row = (tid>>3) + i*32;
            const int k8 = (tid&7)*8;
            *(ushort8_t*)&Bc[row][k8] = *(const ushort8_t*)(Wv_bf + (size_t)(c0+row)*DIM + k0 + k8);
        }
        __syncthreads();
        #pragma unroll
        for (int s = 0; s < 2; ++s) {
            const int kf = s*32 + quad*8;
            bf16x8 a[2], b[4];
            #pragma unroll
            for (int mt = 0; mt < 2; ++mt)
                a[mt] = *(const bf16x8*)&Ap[(wave*2+mt)*16 + l15][kf];
            #pragma unroll
            for (int nt = 0; nt < 4; ++nt)
                b[nt] = *(const bf16x8*)&Bc[nt*16 + l15][kf];
            #pragma unroll
            for (int mt = 0; mt < 2; ++mt)
                #pragma unroll
                for (int nt = 0; nt < 4; ++nt)
                    acc[mt][nt] = __builtin_amdgcn_mfma_f32_16x16x32_bf16(a[mt], b[nt], acc[mt][nt], 0,0,0);
        }
        __syncthreads();
    }
    #pragma unroll
    for (int nt = 0; nt < 4; ++nt) {
        const int c = c0 + nt*16 + l15;
        const float eb = ebias[cam*DIM + c];
        const int h = c >> 5, cc = c & 31;
        unsigned short* vb = value_bf + (size_t)(cam*HEADS + h)*HW_*HDD + cc;
        #pragma unroll
        for (int mt = 0; mt < 2; ++mt)
            #pragma unroll
            for (int r = 0; r < 4; ++r) {
                const int p = p0 + (wave*2+mt)*16 + quad*4 + r;
                vb[(size_t)p*HDD] = f2bf(acc[mt][nt][r] + eb);
            }
    }
}

// ---------------------------------------------------------------------------
// K2a: off/attn GEMM with fused Qr+Pe add/convert, B reg-prefetch, LDS
// epilogue with contiguous stores, and softmax applied in the epilogue
// (attw_ws stores PROBABILITIES).  FROZEN (best-known).
// ---------------------------------------------------------------------------
__global__ __launch_bounds__(256, 3)
void k_offattn(const float* __restrict__ Qr, const float* __restrict__ Pe,
               const unsigned short* __restrict__ Woa_bf,
               const float* __restrict__ boff, const float* __restrict__ battn,
               float* __restrict__ off_ws, float* __restrict__ attw_ws)
{
    __shared__ char smraw[32*204*4];
    unsigned short (*A_lds)[264] = (unsigned short (*)[264])smraw;
    float (*C_lds)[204] = (float (*)[204])smraw;

    const int m0 = blockIdx.x * 32;
    const int tid = threadIdx.x;
    const int lane = tid & 63, wave = tid >> 6;
    const int quad = lane >> 4, l15 = lane & 15;
    const int n0 = wave * 48;

    // --- B prefetch: all 24 fragments, issued before the stage barrier ---
    bf16x8 breg[3][8];
    #pragma unroll
    for (int nt = 0; nt < 3; ++nt) {
        const unsigned short* wb = Woa_bf + (size_t)(n0 + nt*16 + l15)*DIM + quad*8;
        #pragma unroll
        for (int kc = 0; kc < 8; ++kc)
            breg[nt][kc] = *(const bf16x8*)(wb + kc*32);
    }

    // --- A stage: coalesced f32 loads, add, cvt -> LDS ---
    {
        const int row = tid >> 3;       // 0..31
        const int c8  = tid & 7;
        const float* qb = Qr + (size_t)(m0 + row)*DIM;
        const float* pb = Pe + (size_t)(m0 + row)*DIM;
        #pragma unroll
        for (int j = 0; j < 8; ++j) {
            const int col = c8*4 + j*32;
            const float4 x = *(const float4*)(qb + col);
            const float4 y = *(const float4*)(pb + col);
            ushort4 pk;
            pk.x = f2bf(x.x+y.x); pk.y = f2bf(x.y+y.y);
            pk.z = f2bf(x.z+y.z); pk.w = f2bf(x.w+y.w);
            *(ushort4*)&A_lds[row][col] = pk;
        }
    }
    __syncthreads();

    // --- K loop: LDS reads + MFMA only ---
    f32x4 acc[2][3] = {};
    #pragma unroll
    for (int kc = 0; kc < 8; ++kc) {
        const int kk = kc*32 + quad*8;
        const bf16x8 a0 = *(const bf16x8*)&A_lds[l15][kk];
        const bf16x8 a1 = *(const bf16x8*)&A_lds[16 + l15][kk];
        #pragma unroll
        for (int nt = 0; nt < 3; ++nt) {
            acc[0][nt] = __builtin_amdgcn_mfma_f32_16x16x32_bf16(a0, breg[nt][kc], acc[0][nt], 0,0,0);
            acc[1][nt] = __builtin_amdgcn_mfma_f32_16x16x32_bf16(a1, breg[nt][kc], acc[1][nt], 0,0,0);
        }
    }

    // --- epilogue: acc(+bias) -> LDS, softmax on attn cols, contiguous stores
    __syncthreads();   // all A_lds reads done before overwrite
    #pragma unroll
    for (int nt = 0; nt < 3; ++nt) {
        const int col = n0 + nt*16 + l15;
        const float bias = (col < 128) ? boff[col] : battn[col-128];
        #pragma unroll
        for (int mt = 0; mt < 2; ++mt) {
            #pragma unroll
            for (int r = 0; r < 4; ++r)
                C_lds[mt*16 + quad*4 + r][col] = acc[mt][nt][r] + bias;
        }
    }
    __syncthreads();
    // softmax: thread (row = tid>>3, h = tid&7) over 8 contiguous logits
    {
        float* a = &C_lds[tid>>3][128 + (tid&7)*8];
        float lg[8];
        float mx = -1e30f;
        #pragma unroll
        for (int p = 0; p < 8; ++p) { lg[p] = a[p]; mx = fmaxf(mx, lg[p]); }
        float ssum = 0.f;
        #pragma unroll
        for (int p = 0; p < 8; ++p) { lg[p] = __expf(lg[p]-mx); ssum += lg[p]; }
        const float inv = 1.f/ssum;
        #pragma unroll
        for (int p = 0; p < 8; ++p) a[p] = lg[p]*inv;
    }
    __syncthreads();
    // off: 32 rows x 128 f32 = 1024 float4, 4/thread, lane-contiguous
    #pragma unroll
    for (int i = 0; i < 4; ++i) {
        const int idx = i*256 + tid;
        const int row = idx >> 5, c4 = (idx & 31)*4;
        *(float4*)(off_ws + ((size_t)(m0+row))*128 + c4) = *(float4*)&C_lds[row][c4];
    }
    // attw (probabilities): 32 rows x 64 f32 = 512 float4, 2/thread
    #pragma unroll
    for (int i = 0; i < 2; ++i) {
        const int idx = i*256 + tid;
        const int row = idx >> 4, c4 = (idx & 15)*4;
        *(float4*)(attw_ws + ((size_t)(m0+row))*64 + c4) = *(float4*)&C_lds[row][128 + c4];
    }
}

// ---------------------------------------------------------------------------
// K2b: sampling fused with camera reduce.  FROZEN (best-known): quarter-split
// 256 thr, 8q/block, acc[8], VGPR~60.  attw_ws holds probabilities.
// ---------------------------------------------------------------------------
__global__ __launch_bounds__(256)
void k_sample(const unsigned short* __restrict__ value_bf,
              const float* __restrict__ off_ws, const float* __restrict__ attw_ws,
              const float* __restrict__ ref3d, const float* __restrict__ hitf,
              const float* __restrict__ scale, unsigned short* __restrict__ asum_bf)
{
    const int q0 = blockIdx.x * 8;
    const int tid = threadIdx.x;

    __shared__ float s_off[8][128];
    __shared__ float s_att[8][64];
    __shared__ float s_ref[8][8];
    __shared__ float s_hit[BN][8];
    __shared__ float s_scl[8];

    if (tid < 48) s_hit[tid>>3][tid&7] = hitf[(size_t)(tid>>3)*NQ + q0 + (tid&7)];
    if (tid < 8)  s_scl[tid] = scale[q0 + tid];

    const int quarter = tid & 3;
    const int h  = (tid >> 2) & 7;
    const int ql = tid >> 5;

    float acc[8];
    #pragma unroll
    for (int c = 0; c < 8; ++c) acc[c] = 0.f;

    for (int n = 0; n < BN; ++n) {
        __syncthreads();
        {
            const float4* so = (const float4*)(off_ws + ((size_t)n*NQ + q0)*128);
            ((float4*)&s_off[0][0])[tid] = so[tid];
            const float2* sa = (const float2*)(attw_ws + ((size_t)n*NQ + q0)*64);
            ((float2*)&s_att[0][0])[tid] = sa[tid];
            if (tid < 64)
                (&s_ref[0][0])[tid] = (ref3d + ((size_t)n*NQ + q0)*8)[tid];
        }
        __syncthreads();

        if (s_hit[n][ql] != 0.f) {
            const unsigned short* vbase =
                value_bf + (size_t)(n*HEADS + h)*HW_*HDD + quarter*8;

            #pragma unroll
            for (int p = 0; p < 8; ++p) {
                const int z = p & 3;
                const float wp = s_att[ql][h*8+p];   // precomputed probability
                const float ax = s_ref[ql][z*2+0]*WF_ + s_off[ql][h*16+p*2+0] - 0.5f;
                const float ay = s_ref[ql][z*2+1]*HF_ + s_off[ql][h*16+p*2+1] - 0.5f;
                const float fx = floorf(ax), fy = floorf(ay);
                const float dx = ax-fx, dy = ay-fy;
                const int x0 = (int)fx, y0 = (int)fy;
                #pragma unroll
                for (int oy = 0; oy < 2; ++oy) {
                    const int yi = y0 + oy;
                    const float wy = oy ? dy : 1.f-dy;
                    #pragma unroll
                    for (int ox = 0; ox < 2; ++ox) {
                        const int xi = x0 + ox;
                        const float wx = ox ? dx : 1.f-dx;
                        const bool valid = ((unsigned)xi < WF_) & ((unsigned)yi < HF_);
                        const float cw = valid ? wp*wy*wx : 0.f;
                        const int xc = min(max(xi, 0), WF_-1);
                        const int yc = min(max(yi, 0), HF_-1);
                        const ushort8_t v = *(const ushort8_t*)(vbase + (size_t)(yc*WF_ + xc)*HDD);
                        #pragma unroll
                        for (int c = 0; c < 8; ++c)
                            acc[c] += cw * __uint_as_float(((unsigned)v[c]) << 16);
                    }
                }
            }
        }
    }

    const float sc = s_scl[ql];
    ushort8_t o;
    #pragma unroll
    for (int c = 0; c < 8; ++c) o[c] = f2bf(acc[c]*sc);
    *(ushort8_t*)(asum_bf + ((size_t)(q0+ql))*DIM + h*HDD + quarter*8) = o;
}

// ---------------------------------------------------------------------------
// K_tail: FUSED inner+output projection.  Per 32-row block:
//   phase 1: S = asum·Wi^T + biasf(m)*bi   -> bf16 S_lds[32][264]
//   phase 2: out = S·Wz^T + bz             -> f32, coalesced via C_lds
// Replaces the two k_gemm_mfma launches and the 5.1 MB slots_bf round-trip.
// A frags per-lane direct from L2-hot asum_bf (r2 pattern); B in-loop from
// L2-resident 128 KB weight panels; grid 313 blocks.
// ---------------------------------------------------------------------------
__global__ __launch_bounds__(256)
void k_tail(const unsigned short* __restrict__ asum_bf,
            const unsigned short* __restrict__ Wi_bf,
            const unsigned short* __restrict__ Wz_bf,
            const float* __restrict__ bi, const float* __restrict__ bz,
            const float* __restrict__ biasf, float* __restrict__ out)
{
    __shared__ char smraw[32*260*4];   // union: S_lds bf16[32][264] / C_lds f32[32][260]
    unsigned short (*S_lds)[264] = (unsigned short (*)[264])smraw;
    float (*C_lds)[260] = (float (*)[260])smraw;

    const int m0 = blockIdx.x * 32;
    const int tid = threadIdx.x;
    const int lane = tid & 63, wave = tid >> 6;
    const int quad = lane >> 4, l15 = lane & 15;
    const int n0 = wave * 64;

    const int r0 = m0 + l15;
    const int r1 = m0 + 16 + l15;
    const unsigned short* a0p = asum_bf + (size_t)(r0 < NQ ? r0 : 0)*DIM;
    const unsigned short* a1p = asum_bf + (size_t)(r1 < NQ ? r1 : 0)*DIM;

    // --- phase 1: S = asum · Wi^T ---
    f32x4 acc[2][4] = {};
    #pragma unroll
    for (int kc = 0; kc < 8; ++kc) {
        const int kk = kc*32 + quad*8;
        const bf16x8 a0 = *(const bf16x8*)(a0p + kk);
        const bf16x8 a1 = *(const bf16x8*)(a1p + kk);
        #pragma unroll
        for (int nt = 0; nt < 4; ++nt) {
            const bf16x8 b = *(const bf16x8*)(Wi_bf + (size_t)(n0 + nt*16 + l15)*DIM + kk);
            acc[0][nt] = __builtin_amdgcn_mfma_f32_16x16x32_bf16(a0, b, acc[0][nt], 0,0,0);
            acc[1][nt] = __builtin_amdgcn_mfma_f32_16x16x32_bf16(a1, b, acc[1][nt], 0,0,0);
        }
    }
    #pragma unroll
    for (int nt = 0; nt < 4; ++nt) {
        const int col = n0 + nt*16 + l15;
        const float bj = bi[col];
        #pragma unroll
        for (int mt = 0; mt < 2; ++mt) {
            #pragma unroll
            for (int r = 0; r < 4; ++r) {
                const int m = m0 + mt*16 + quad*4 + r;
                const float f = (m < NQ) ? biasf[m] : 0.f;
                S_lds[mt*16 + quad*4 + r][col] = f2bf(acc[mt][nt][r] + f*bj);
            }
        }
    }
    __syncthreads();

    // --- phase 2: out = S · Wz^T ---
    f32x4 acc2[2][4] = {};
    #pragma unroll
    for (int kc = 0; kc < 8; ++kc) {
        const int kk = kc*32 + quad*8;
        const bf16x8 s0 = *(const bf16x8*)&S_lds[l15][kk];
        const bf16x8 s1 = *(const bf16x8*)&S_lds[16 + l15][kk];
        #pragma unroll
        for (int nt = 0; nt < 4; ++nt) {
            const bf16x8 b = *(const bf16x8*)(Wz_bf + (size_t)(n0 + nt*16 + l15)*DIM + kk);
            acc2[0][nt] = __builtin_amdgcn_mfma_f32_16x16x32_bf16(s0, b, acc2[0][nt], 0,0,0);
            acc2[1][nt] = __builtin_amdgcn_mfma_f32_16x16x32_bf16(s1, b, acc2[1][nt], 0,0,0);
        }
    }
    __syncthreads();   // all S_lds reads done before C_lds overwrite
    #pragma unroll
    for (int nt = 0; nt < 4; ++nt) {
        const int col = n0 + nt*16 + l15;
        const float bj = bz[col];
        #pragma unroll
        for (int mt = 0; mt < 2; ++mt) {
            #pragma unroll
            for (int r = 0; r < 4; ++r)
                C_lds[mt*16 + quad*4 + r][col] = acc2[mt][nt][r] + bj;
        }
    }
    __syncthreads();
    // coalesced stores: 32 rows x 256 f32 = 2048 float4, 8/thread
    #pragma unroll
    for (int i = 0; i < 8; ++i) {
        const int idx = i*256 + tid;
        const int row = idx >> 6, c4 = (idx & 63)*4;
        const int m = m0 + row;
        if (m < NQ)
            *(float4*)(out + (size_t)m*DIM + c4) = *(float4*)&C_lds[row][c4];
    }
}

// ---------------------------------------------------------------------------
extern "C" void kernel_launch(void* const* d_in, const int* in_sizes, int n_in,
                              void* d_out, int out_size, void* d_ws, size_t ws_size,
                              hipStream_t stream)
{
    const float* queries = (const float*)d_in[0];
    const float* pos_emb = (const float*)d_in[1];
    const float* lvl_emb = (const float*)d_in[2];
    const float* cam_emb = (const float*)d_in[3];
    const float* features= (const float*)d_in[4];
    const float* ref3d   = (const float*)d_in[5];
    const int*   bev     = (const int*)d_in[6];
    const float* Wv = (const float*)d_in[7];
    const float* bv = (const float*)d_in[8];
    const float* Wo = (const float*)d_in[9];
    const float* bo = (const float*)d_in[10];
    const float* Wa = (const float*)d_in[11];
    const float* ba = (const float*)d_in[12];
    const float* Wi = (const float*)d_in[13];
    const float* bi = (const float*)d_in[14];
    const float* Wz = (const float*)d_in[15];
    const float* bz = (const float*)d_in[16];
    float* out = (float*)d_out;

    char* ws = (char*)d_ws;
    size_t o = 0;
    auto alloc = [&](size_t bytes) { char* p = ws + o; o += (bytes + 255) & ~size_t(255); return p; };
    unsigned short* value_bf = (unsigned short*)alloc((size_t)BN*HEADS*HW_*HDD*2);  // 8.65 MB
    unsigned short* featT    = (unsigned short*)alloc((size_t)BN*HW_*DIM*2);        // 8.65 MB
    float* off_ws   = (float*)alloc((size_t)MTOT*128*4);                            // 30.7 MB
    float* attw_ws  = (float*)alloc((size_t)MTOT*64*4);                             // 15.4 MB
    unsigned short* asum_bf  = (unsigned short*)alloc((size_t)NQ*DIM*2);            // 5.1 MB
    unsigned short* Wv_bf  = (unsigned short*)alloc(65536*2);
    unsigned short* Woa_bf = (unsigned short*)alloc(49152*2);
    unsigned short* Wi_bf  = (unsigned short*)alloc(65536*2);
    unsigned short* Wz_bf  = (unsigned short*)alloc(65536*2);
    float* hitf   = (float*)alloc((size_t)BN*NQ*4);
    float* scalev = (float*)alloc(NQ*4);
    float* biasf  = (float*)alloc(NQ*4);
    float* ebias  = (float*)alloc(BN*DIM*4);
    // total ~69 MB

    k_prep  <<<110, 256, 0, stream>>>(Wv, Wo, Wa, Wi, Wz, lvl_emb, cam_emb, bv, bev,
                                      Wv_bf, Woa_bf, Wi_bf, Wz_bf,
                                      ebias, hitf, scalev, biasf);
    k_feat  <<<dim3(HW_/64, DIM/64, BN), 256, 0, stream>>>(features, featT);
    k_value_mfma<<<dim3(HW_/128, DIM/64, BN), 256, 0, stream>>>(featT, Wv_bf, ebias, value_bf);
    k_offattn<<<MTOT/32, 256, 0, stream>>>(queries, pos_emb, Woa_bf, bo, ba, off_ws, attw_ws);
    k_sample <<<NQ/8, 256, 0, stream>>>(value_bf, off_ws, attw_ws, ref3d, hitf, scalev, asum_bf);
    k_tail   <<<(NQ+31)/32, 256, 0, stream>>>(asum_bf, Wi_bf, Wz_bf, bi, bz, biasf, out);
}